// Round 7
// baseline (322.703 us; speedup 1.0000x reference)
//
#include <hip/hip_runtime.h>

#define N_NODES 50000
#define N_EDGES 800000
#define E_TOT   (N_EDGES + N_NODES)   // 850000, self-loops appended at end
#define SCAN_B  ((N_NODES + 255) / 256)  // 196

using bfrag = __attribute__((ext_vector_type(8))) short;
using f32x4 = __attribute__((ext_vector_type(4))) float;

// ---------------------------------------------------------------- bf16 helpers
__device__ __forceinline__ float bflo(unsigned int p) {
  union { unsigned int u; float f; } v; v.u = p << 16; return v.f;
}
__device__ __forceinline__ float bfhi(unsigned int p) {
  union { unsigned int u; float f; } v; v.u = p & 0xFFFF0000u; return v.f;
}
__device__ __forceinline__ unsigned short f2bf(float f) {
  union { float f; unsigned int u; } v; v.f = f;
  unsigned int r = v.u + 0x7FFFu + ((v.u >> 16) & 1u);
  return (unsigned short)(r >> 16);
}
__device__ __forceinline__ void unpack8(uint4 u, float* hv) {
  hv[0] = bflo(u.x); hv[1] = bfhi(u.x);
  hv[2] = bflo(u.y); hv[3] = bfhi(u.y);
  hv[4] = bflo(u.z); hv[5] = bfhi(u.z);
  hv[6] = bflo(u.w); hv[7] = bfhi(u.w);
}

// ---------------------------------------------------------------- conversions
__global__ void k_f2bf(const float* __restrict__ in, unsigned short* __restrict__ out,
                       int n4) {
  int i = blockIdx.x * blockDim.x + threadIdx.x;
  if (i >= n4) return;
  float4 v = *(const float4*)&in[(size_t)i * 4];
  *(ushort4*)&out[(size_t)i * 4] =
      make_ushort4(f2bf(v.x), f2bf(v.y), f2bf(v.z), f2bf(v.w));
}

// W[K][N] fp32 -> Wt[N][K] bf16
template <int K, int N>
__global__ void k_wt(const float* __restrict__ W, unsigned short* __restrict__ Wt) {
  int i = blockIdx.x * blockDim.x + threadIdx.x;
  if (i >= K * N) return;
  int k = i / N, n = i - k * N;
  Wt[n * K + k] = f2bf(W[i]);
}

// w~[h] = W1[:, h*64:+64] @ att[h]  (fp32), layout wtl[{s,d}][h][128]
__global__ void k_wtld(const float* __restrict__ W1, const float* __restrict__ as1,
                       const float* __restrict__ ad1, float* __restrict__ wtl) {
  int t = blockIdx.x * blockDim.x + threadIdx.x;
  if (t >= 512) return;
  int h = t >> 7, k = t & 127;
  float s = 0.f, d = 0.f;
  for (int c = 0; c < 64; ++c) {
    float w = W1[k * 256 + h * 64 + c];
    s += w * as1[h * 64 + c];
    d += w * ad1[h * 64 + c];
  }
  wtl[h * 128 + k]       = s;
  wtl[512 + h * 128 + k] = d;
}

// aS/aD[n][h] = <x[n], w~[h]>  (wave per node)
__global__ __launch_bounds__(256) void k_attx(
    const float* __restrict__ x, const float* __restrict__ wtl,
    float* __restrict__ aS, float* __restrict__ aD) {
  __shared__ float wls[1024];
  int t = threadIdx.x;
  for (int i = t; i < 1024; i += 256) wls[i] = wtl[i];
  __syncthreads();
  int n = (int)((blockIdx.x * 256 + t) >> 6);
  int lane = t & 63;
  if (n >= N_NODES) return;
  float2 xv = *(const float2*)&x[(size_t)n * 128 + lane * 2];
  float ps[4], pd[4];
  #pragma unroll
  for (int h = 0; h < 4; ++h) {
    ps[h] = xv.x * wls[h * 128 + lane * 2] + xv.y * wls[h * 128 + lane * 2 + 1];
    pd[h] = xv.x * wls[512 + h * 128 + lane * 2] + xv.y * wls[512 + h * 128 + lane * 2 + 1];
  }
  #pragma unroll
  for (int off = 1; off < 64; off <<= 1)
    #pragma unroll
    for (int h = 0; h < 4; ++h) {
      ps[h] += __shfl_xor(ps[h], off);
      pd[h] += __shfl_xor(pd[h], off);
    }
  if (lane == 0) {
    *(float4*)&aS[(size_t)n * 4] = make_float4(ps[0], ps[1], ps[2], ps[3]);
    *(float4*)&aD[(size_t)n * 4] = make_float4(pd[0], pd[1], pd[2], pd[3]);
  }
}

// ---------------------------------------------------------------- CSR build
__global__ void k_hist(const int* __restrict__ ei, int* __restrict__ cnt) {
  int e = blockIdx.x * blockDim.x + threadIdx.x;
  if (e >= E_TOT) return;
  int d = (e < N_EDGES) ? ei[N_EDGES + e] : (e - N_EDGES);
  atomicAdd(&cnt[d], 1);
}

__global__ void k_bsum(const int* __restrict__ cnt, int* __restrict__ bsum) {
  int t = threadIdx.x;
  int i = blockIdx.x * 256 + t;
  int v = (i < N_NODES) ? cnt[i] : 0;
  #pragma unroll
  for (int off = 32; off; off >>= 1) v += __shfl_down(v, off);
  __shared__ int ws[4];
  if ((t & 63) == 0) ws[t >> 6] = v;
  __syncthreads();
  if (t == 0) bsum[blockIdx.x] = ws[0] + ws[1] + ws[2] + ws[3];
}

__global__ void k_bscan(const int* __restrict__ bsum, int* __restrict__ boff) {
  __shared__ int s[256];
  int t = threadIdx.x;
  int v = (t < SCAN_B) ? bsum[t] : 0;
  s[t] = v;
  __syncthreads();
  for (int off = 1; off < 256; off <<= 1) {
    int x = (t >= off) ? s[t - off] : 0;
    __syncthreads();
    s[t] += x;
    __syncthreads();
  }
  boff[t] = s[t] - v;  // exclusive
}

__global__ void k_rowptr(const int* __restrict__ cnt, const int* __restrict__ boff,
                         int* __restrict__ rowptr, int* __restrict__ cursor) {
  __shared__ int s[256];
  int t = threadIdx.x;
  int i = blockIdx.x * 256 + t;
  int v = (i < N_NODES) ? cnt[i] : 0;
  s[t] = v;
  __syncthreads();
  for (int off = 1; off < 256; off <<= 1) {
    int x = (t >= off) ? s[t - off] : 0;
    __syncthreads();
    s[t] += x;
    __syncthreads();
  }
  int excl = boff[blockIdx.x] + s[t] - v;
  if (i < N_NODES) { rowptr[i] = excl; cursor[i] = excl; }
  if (i == N_NODES - 1) rowptr[N_NODES] = excl + v;
}

__global__ void k_scatter(const int* __restrict__ ei, int* __restrict__ cursor,
                          int* __restrict__ csr) {
  int e = blockIdx.x * blockDim.x + threadIdx.x;
  if (e >= E_TOT) return;
  int s, d;
  if (e < N_EDGES) { s = ei[e]; d = ei[N_EDGES + e]; }
  else             { s = d = e - N_EDGES; }
  int pos = atomicAdd(&cursor[d], 1);
  csr[pos] = s;
}

// ------------------------------------------- MFMA bf16 GEMM + fused epilogue
// Full-width: one block computes ALL H heads (NN = H*64 cols) for 64 rows.
template <int KD, int H>
__global__ __launch_bounds__(256) void k_gemm_mfma(
    const unsigned short* __restrict__ Aq, const unsigned short* __restrict__ Wt,
    const float* __restrict__ atts, const float* __restrict__ attd,
    unsigned short* __restrict__ hq, float* __restrict__ aS,
    float* __restrict__ aD, int M) {
  constexpr int NN = H * 64;
  constexpr int KH = KD / 2;              // K per half
  constexpr int GR = KH / 8;              // 16B granules per col per half
  __shared__ unsigned short Bts[NN * KH]; // 32 KB
  int t = threadIdx.x;
  int lane = t & 63;
  int w = t >> 6;
  int arow = blockIdx.x * 64 + w * 16 + (lane & 15);
  int arow_c = arow < M ? arow : M - 1;
  const unsigned short* Arow = Aq + (size_t)arow_c * KD;

  f32x4 acc[NN / 16] = {};
  #pragma unroll
  for (int half = 0; half < 2; ++half) {
    if (half) __syncthreads();
    #pragma unroll
    for (int c = 0; c < NN * KH / 2048; ++c) {
      int chunk = t + c * 256;
      int col = chunk / GR;
      int kc  = chunk % GR;
      uint4 v = *(const uint4*)&Wt[(size_t)col * KD + half * KH + kc * 8];
      int swz = kc ^ (col & 7);
      *(uint4*)&Bts[col * KH + swz * 8] = v;
    }
    __syncthreads();
    for (int k0 = 0; k0 < KH; k0 += 32) {
      int gl = (k0 >> 3) + (lane >> 4);
      bfrag a = *(const bfrag*)&Arow[half * KH + gl * 8];
      #pragma unroll
      for (int cf = 0; cf < NN / 16; ++cf) {
        int col = cf * 16 + (lane & 15);
        int gs = gl ^ (col & 7);
        bfrag b = *(const bfrag*)&Bts[col * KH + gs * 8];
        acc[cf] = __builtin_amdgcn_mfma_f32_16x16x32_bf16(a, b, acc[cf], 0, 0, 0);
      }
    }
  }

  float ws_[NN / 16], wd_[NN / 16];
  #pragma unroll
  for (int cf = 0; cf < NN / 16; ++cf) {
    ws_[cf] = atts[cf * 16 + (lane & 15)];
    wd_[cf] = attd[cf * 16 + (lane & 15)];
  }
  int orow0 = blockIdx.x * 64 + w * 16 + (lane >> 4) * 4;
  #pragma unroll
  for (int hh = 0; hh < H; ++hh) {
    float ps[4] = {}, pd[4] = {};
    #pragma unroll
    for (int c4 = 0; c4 < 4; ++c4) {
      int cf = hh * 4 + c4;
      #pragma unroll
      for (int i = 0; i < 4; ++i) {
        ps[i] += acc[cf][i] * ws_[cf];
        pd[i] += acc[cf][i] * wd_[cf];
      }
    }
    #pragma unroll
    for (int off = 1; off < 16; off <<= 1)
      #pragma unroll
      for (int i = 0; i < 4; ++i) {
        ps[i] += __shfl_xor(ps[i], off);
        pd[i] += __shfl_xor(pd[i], off);
      }
    if ((lane & 15) == 0)
      #pragma unroll
      for (int i = 0; i < 4; ++i) {
        int r = orow0 + i;
        if (r < M) {
          aS[(size_t)r * H + hh] = ps[i];
          aD[(size_t)r * H + hh] = pd[i];
        }
      }
  }
  #pragma unroll
  for (int i = 0; i < 4; ++i) {
    int r = orow0 + i;
    if (r < M)
      #pragma unroll
      for (int cf = 0; cf < NN / 16; ++cf)
        hq[(size_t)r * NN + cf * 16 + (lane & 15)] = f2bf(acc[cf][i]);
  }
}

// ---------------- block-diagonal GEMM for layer-1: out[n, h*64+c] =
// ELU( aggX[n, h*128:+128] @ W1[:, h*64+c] + b1[h*64+c] ), bf16 out.
__global__ __launch_bounds__(256) void k_gemm_bd(
    const unsigned short* __restrict__ aggX, const unsigned short* __restrict__ Wt,
    const float* __restrict__ b1, unsigned short* __restrict__ hq, int M) {
  __shared__ unsigned short Bts[64 * 128];  // 16 KB
  int t = threadIdx.x;
  int hh = blockIdx.y;
  // stage W1t cols [hh*64, +64), all 128 K, swizzled
  #pragma unroll
  for (int c = 0; c < 4; ++c) {
    int chunk = t + c * 256;
    int col = chunk >> 4;        // /16 granules per col
    int kc  = chunk & 15;
    uint4 v = *(const uint4*)&Wt[(size_t)(hh * 64 + col) * 128 + kc * 8];
    int swz = kc ^ (col & 7);
    *(uint4*)&Bts[col * 128 + swz * 8] = v;
  }
  __syncthreads();

  int lane = t & 63;
  int w = t >> 6;
  int arow = blockIdx.x * 64 + w * 16 + (lane & 15);
  int arow_c = arow < M ? arow : M - 1;
  const unsigned short* Arow = aggX + (size_t)arow_c * 512 + hh * 128;

  f32x4 acc[4] = {};
  for (int k0 = 0; k0 < 128; k0 += 32) {
    int g = (k0 >> 3) + (lane >> 4);
    bfrag a = *(const bfrag*)&Arow[g * 8];
    #pragma unroll
    for (int cf = 0; cf < 4; ++cf) {
      int col = cf * 16 + (lane & 15);
      int gs = g ^ (col & 7);
      bfrag b = *(const bfrag*)&Bts[col * 128 + gs * 8];
      acc[cf] = __builtin_amdgcn_mfma_f32_16x16x32_bf16(a, b, acc[cf], 0, 0, 0);
    }
  }

  int orow0 = blockIdx.x * 64 + w * 16 + (lane >> 4) * 4;
  #pragma unroll
  for (int i = 0; i < 4; ++i) {
    int r = orow0 + i;
    if (r < M)
      #pragma unroll
      for (int cf = 0; cf < 4; ++cf) {
        int c = cf * 16 + (lane & 15);
        float v = acc[cf][i] + b1[hh * 64 + c];
        v = v > 0.f ? v : __expf(v) - 1.f;
        hq[(size_t)r * 256 + hh * 64 + c] = f2bf(v);
      }
  }
}

// -------------- layer-1 aggregation over RAW x: gather xq rows (256B), 4-head
// weighted sums -> aggX [N][4][128] bf16. 3-phase LDS staging as before.
__global__ __launch_bounds__(256) void k_aggrX(
    const int* __restrict__ rowptr, const int* __restrict__ csr,
    const unsigned short* __restrict__ xq,
    const float* __restrict__ aS, const float* __restrict__ aD,
    unsigned short* __restrict__ aggX) {
  constexpr int CAP = 64;
  __shared__ int   jls[4][CAP];
  __shared__ float wls[4][CAP * 4];
  int n    = (int)((blockIdx.x * (size_t)blockDim.x + threadIdx.x) >> 6);
  int lane = threadIdx.x & 63;
  int wsl  = threadIdx.x >> 6;
  if (n >= N_NODES) return;
  int* jl  = jls[wsl];
  float* wl = wls[wsl];
  int cg  = lane & 15;   // channel group: x channels cg*8 .. cg*8+7
  int sub = lane >> 4;   // which edge of the 4-pack

  float ad[4];
  #pragma unroll
  for (int h = 0; h < 4; ++h) ad[h] = aD[(size_t)n * 4 + h];

  int lo = rowptr[n], deg = rowptr[n + 1] - lo;
  float m[4], s[4];
  float acc[4][8] = {};
  #pragma unroll
  for (int h = 0; h < 4; ++h) { m[h] = -1e30f; s[h] = 0.f; }

  for (int c0 = 0; c0 < deg; c0 += CAP) {
    int cl = deg - c0; if (cl > CAP) cl = CAP;
    // ---- phase 0a: stage j, leaky(e); chunk max
    float cmx[4];
    #pragma unroll
    for (int h = 0; h < 4; ++h) cmx[h] = -1e30f;
    for (int kk = lane; kk < cl; kk += 64) {
      int j = csr[lo + c0 + kk];
      jl[kk] = j;
      float4 a4 = *(const float4*)&aS[(size_t)j * 4];
      float e[4] = {a4.x, a4.y, a4.z, a4.w};
      #pragma unroll
      for (int h = 0; h < 4; ++h) {
        float v = e[h] + ad[h];
        v = v > 0.f ? v : 0.2f * v;
        e[h] = v;
        cmx[h] = fmaxf(cmx[h], v);
      }
      *(float4*)&wl[kk * 4] = make_float4(e[0], e[1], e[2], e[3]);
    }
    #pragma unroll
    for (int off = 1; off < 64; off <<= 1)
      #pragma unroll
      for (int h = 0; h < 4; ++h)
        cmx[h] = fmaxf(cmx[h], __shfl_xor(cmx[h], off));
    float nm[4], fac[4], cs[4];
    #pragma unroll
    for (int h = 0; h < 4; ++h) {
      nm[h] = fmaxf(m[h], cmx[h]);
      fac[h] = __expf(m[h] - nm[h]);
      cs[h] = 0.f;
    }
    __builtin_amdgcn_wave_barrier();
    // ---- phase 0b: w = exp(e - nm), chunk denom
    for (int kk = lane; kk < cl; kk += 64) {
      float4 tv = *(const float4*)&wl[kk * 4];
      float e[4] = {tv.x, tv.y, tv.z, tv.w};
      #pragma unroll
      for (int h = 0; h < 4; ++h) {
        float w = __expf(e[h] - nm[h]);
        e[h] = w;
        cs[h] += w;
      }
      *(float4*)&wl[kk * 4] = make_float4(e[0], e[1], e[2], e[3]);
    }
    #pragma unroll
    for (int off = 1; off < 64; off <<= 1)
      #pragma unroll
      for (int h = 0; h < 4; ++h)
        cs[h] += __shfl_xor(cs[h], off);
    #pragma unroll
    for (int h = 0; h < 4; ++h) {
      s[h] = s[h] * fac[h] + cs[h];
      m[h] = nm[h];
      #pragma unroll
      for (int i = 0; i < 8; ++i) acc[h][i] *= fac[h];
    }
    __builtin_amdgcn_wave_barrier();
    // ---- phase 1: 2D gather of x rows (4 edges per wave instr)
    #pragma unroll 2
    for (int k = 0; k < cl; k += 4) {
      int idx = k + sub;
      bool v = idx < cl;
      int j = jl[v ? idx : 0];
      float w0 = v ? wl[idx * 4 + 0] : 0.f;
      float w1 = v ? wl[idx * 4 + 1] : 0.f;
      float w2 = v ? wl[idx * 4 + 2] : 0.f;
      float w3 = v ? wl[idx * 4 + 3] : 0.f;
      uint4 u = *(const uint4*)&xq[(size_t)j * 128 + cg * 8];
      float hv[8];
      unpack8(u, hv);
      #pragma unroll
      for (int i = 0; i < 8; ++i) {
        acc[0][i] += w0 * hv[i];
        acc[1][i] += w1 * hv[i];
        acc[2][i] += w2 * hv[i];
        acc[3][i] += w3 * hv[i];
      }
    }
    __builtin_amdgcn_wave_barrier();
  }

  // fold the 4 edge-subgroups (stride-16 lanes share cg)
  #pragma unroll
  for (int h = 0; h < 4; ++h)
    #pragma unroll
    for (int i = 0; i < 8; ++i) {
      acc[h][i] += __shfl_xor(acc[h][i], 16);
      acc[h][i] += __shfl_xor(acc[h][i], 32);
    }

  if (sub == 0) {
    #pragma unroll
    for (int h = 0; h < 4; ++h) {
      float inv = 1.f / s[h];
      uint4 r;
      r.x = (unsigned int)f2bf(acc[h][0] * inv) | ((unsigned int)f2bf(acc[h][1] * inv) << 16);
      r.y = (unsigned int)f2bf(acc[h][2] * inv) | ((unsigned int)f2bf(acc[h][3] * inv) << 16);
      r.z = (unsigned int)f2bf(acc[h][4] * inv) | ((unsigned int)f2bf(acc[h][5] * inv) << 16);
      r.w = (unsigned int)f2bf(acc[h][6] * inv) | ((unsigned int)f2bf(acc[h][7] * inv) << 16);
      *(uint4*)&aggX[(size_t)n * 512 + h * 128 + cg * 8] = r;
    }
  }
}

// -------------- edge-softmax + aggregate (layer 2), 3-phase LDS staging,
// 2D edge x channel-group gather (H=2: 4 edges per wave instr).
template <int H, bool ELU, bool OBF>
__global__ __launch_bounds__(256) void k_aggr(
    const int* __restrict__ rowptr, const int* __restrict__ csr,
    const unsigned short* __restrict__ hq,
    const float* __restrict__ aS, const float* __restrict__ aD,
    const float* __restrict__ bias, void* __restrict__ outv) {
  constexpr int CAP = 64;
  constexpr int C = H * 64;
  constexpr int EPW = 512 / C;
  constexpr int LPE = 64 / EPW;
  __shared__ int   jls[4][CAP];
  __shared__ float wls[4][CAP * H];
  int n    = (int)((blockIdx.x * (size_t)blockDim.x + threadIdx.x) >> 6);
  int lane = threadIdx.x & 63;
  int wsl  = threadIdx.x >> 6;
  if (n >= N_NODES) return;
  int* jl  = jls[wsl];
  float* wl = wls[wsl];
  int cg  = lane & (LPE - 1);
  int sub = lane / LPE;
  int hlc = cg >> 3;

  float ad[H];
  #pragma unroll
  for (int h = 0; h < H; ++h) ad[h] = aD[(size_t)n * H + h];

  int lo = rowptr[n], deg = rowptr[n + 1] - lo;
  float m[H], s[H];
  float acc8[8] = {};
  #pragma unroll
  for (int h = 0; h < H; ++h) { m[h] = -1e30f; s[h] = 0.f; }

  for (int c0 = 0; c0 < deg; c0 += CAP) {
    int cl = deg - c0; if (cl > CAP) cl = CAP;
    float cmx[H];
    #pragma unroll
    for (int h = 0; h < H; ++h) cmx[h] = -1e30f;
    for (int kk = lane; kk < cl; kk += 64) {
      int j = csr[lo + c0 + kk];
      jl[kk] = j;
      float e[H];
      if constexpr (H == 4) {
        float4 a4 = *(const float4*)&aS[(size_t)j * 4];
        e[0] = a4.x; e[1] = a4.y; e[2] = a4.z; e[3] = a4.w;
      } else {
        float2 a2 = *(const float2*)&aS[(size_t)j * 2];
        e[0] = a2.x; e[1] = a2.y;
      }
      #pragma unroll
      for (int h = 0; h < H; ++h) {
        float v = e[h] + ad[h];
        v = v > 0.f ? v : 0.2f * v;
        e[h] = v;
        cmx[h] = fmaxf(cmx[h], v);
      }
      if constexpr (H == 4)
        *(float4*)&wl[kk * 4] = make_float4(e[0], e[1], e[2], e[3]);
      else
        *(float2*)&wl[kk * 2] = make_float2(e[0], e[1]);
    }
    #pragma unroll
    for (int off = 1; off < 64; off <<= 1)
      #pragma unroll
      for (int h = 0; h < H; ++h)
        cmx[h] = fmaxf(cmx[h], __shfl_xor(cmx[h], off));
    float nm[H], fac[H], cs[H];
    #pragma unroll
    for (int h = 0; h < H; ++h) {
      nm[h] = fmaxf(m[h], cmx[h]);
      fac[h] = __expf(m[h] - nm[h]);
      cs[h] = 0.f;
    }
    __builtin_amdgcn_wave_barrier();
    for (int kk = lane; kk < cl; kk += 64) {
      float e[H];
      if constexpr (H == 4) {
        float4 t = *(const float4*)&wl[kk * 4];
        e[0] = t.x; e[1] = t.y; e[2] = t.z; e[3] = t.w;
      } else {
        float2 t = *(const float2*)&wl[kk * 2];
        e[0] = t.x; e[1] = t.y;
      }
      #pragma unroll
      for (int h = 0; h < H; ++h) {
        float w = __expf(e[h] - nm[h]);
        e[h] = w;
        cs[h] += w;
      }
      if constexpr (H == 4)
        *(float4*)&wl[kk * 4] = make_float4(e[0], e[1], e[2], e[3]);
      else
        *(float2*)&wl[kk * 2] = make_float2(e[0], e[1]);
    }
    #pragma unroll
    for (int off = 1; off < 64; off <<= 1)
      #pragma unroll
      for (int h = 0; h < H; ++h)
        cs[h] += __shfl_xor(cs[h], off);
    #pragma unroll
    for (int h = 0; h < H; ++h) {
      s[h] = s[h] * fac[h] + cs[h];
      m[h] = nm[h];
    }
    float facl = fac[hlc];
    #pragma unroll
    for (int i = 0; i < 8; ++i) acc8[i] *= facl;
    __builtin_amdgcn_wave_barrier();
    #pragma unroll 2
    for (int k = 0; k < cl; k += EPW) {
      int idx = k + sub;
      bool v = idx < cl;
      int j = jl[v ? idx : 0];
      float wgt = v ? wl[idx * H + hlc] : 0.f;
      uint4 u = *(const uint4*)&hq[(size_t)j * C + cg * 8];
      float hv[8];
      unpack8(u, hv);
      #pragma unroll
      for (int i = 0; i < 8; ++i) acc8[i] += wgt * hv[i];
    }
    __builtin_amdgcn_wave_barrier();
  }

  #pragma unroll
  for (int i = 0; i < 8; ++i) {
    if constexpr (EPW == 4) acc8[i] += __shfl_xor(acc8[i], 16);
    acc8[i] += __shfl_xor(acc8[i], 32);
  }

  if (sub == 0) {
    float inv = 1.f / s[hlc];
    float o[8];
    #pragma unroll
    for (int i = 0; i < 8; ++i) {
      float v = acc8[i] * inv + bias[cg * 8 + i];
      if (ELU) v = v > 0.f ? v : __expf(v) - 1.f;
      o[i] = v;
    }
    size_t idx = (size_t)n * C + cg * 8;
    if constexpr (OBF) {
      unsigned short* outp = (unsigned short*)outv;
      uint4 r;
      r.x = (unsigned int)f2bf(o[0]) | ((unsigned int)f2bf(o[1]) << 16);
      r.y = (unsigned int)f2bf(o[2]) | ((unsigned int)f2bf(o[3]) << 16);
      r.z = (unsigned int)f2bf(o[4]) | ((unsigned int)f2bf(o[5]) << 16);
      r.w = (unsigned int)f2bf(o[6]) | ((unsigned int)f2bf(o[7]) << 16);
      *(uint4*)&outp[idx] = r;
    } else {
      float* outp = (float*)outv;
      *(float4*)&outp[idx]     = make_float4(o[0], o[1], o[2], o[3]);
      *(float4*)&outp[idx + 4] = make_float4(o[4], o[5], o[6], o[7]);
    }
  }
}

// --------------------------------------------------------- layer-3 (C=2, H=1)
__global__ void k_proj3(const float* __restrict__ hin, const float* __restrict__ W3,
                        const float* __restrict__ s3, const float* __restrict__ d3,
                        float* __restrict__ h3, float* __restrict__ a3s,
                        float* __restrict__ a3d) {
  int n = blockIdx.x * blockDim.x + threadIdx.x;
  if (n >= N_NODES) return;
  float a0 = 0.f, a1 = 0.f;
  const float4* hp = (const float4*)(hin + (size_t)n * 128);
  #pragma unroll
  for (int q = 0; q < 32; ++q) {
    float4 v = hp[q];
    const float* w = W3 + q * 8;
    a0 += v.x * w[0] + v.y * w[2] + v.z * w[4] + v.w * w[6];
    a1 += v.x * w[1] + v.y * w[3] + v.z * w[5] + v.w * w[7];
  }
  h3[(size_t)n * 2]     = a0;
  h3[(size_t)n * 2 + 1] = a1;
  a3s[n] = a0 * s3[0] + a1 * s3[1];
  a3d[n] = a0 * d3[0] + a1 * d3[1];
}

__global__ void k_aggr3(const int* __restrict__ rowptr, const int* __restrict__ csr,
                        const float* __restrict__ h3, const float* __restrict__ a3s,
                        const float* __restrict__ a3d, const float* __restrict__ b3,
                        float* __restrict__ out) {
  int n = blockIdx.x * blockDim.x + threadIdx.x;
  if (n >= N_NODES) return;
  float adv = a3d[n];
  float m = -1e30f, s = 0.f, acc0 = 0.f, acc1 = 0.f;
  int lo = rowptr[n], hi = rowptr[n + 1];
  for (int k = lo; k < hi; ++k) {
    int j = csr[k];
    float e = a3s[j] + adv;
    e = e > 0.f ? e : 0.2f * e;
    float h0 = h3[(size_t)j * 2], h1 = h3[(size_t)j * 2 + 1];
    float nm = fmaxf(m, e);
    float sc = __expf(m - nm);
    float w  = __expf(e - nm);
    s = s * sc + w; acc0 = acc0 * sc + w * h0; acc1 = acc1 * sc + w * h1;
    m = nm;
  }
  float o0 = acc0 / s + b3[0];
  float o1 = acc1 / s + b3[1];
  float mx = fmaxf(o0, o1);
  float l  = logf(__expf(o0 - mx) + __expf(o1 - mx));
  out[(size_t)n * 2]     = o0 - mx - l;
  out[(size_t)n * 2 + 1] = o1 - mx - l;
}

// ---------------------------------------------------------------- launcher
extern "C" void kernel_launch(void* const* d_in, const int* in_sizes, int n_in,
                              void* d_out, int out_size, void* d_ws, size_t ws_size,
                              hipStream_t stream) {
  const float* x   = (const float*)d_in[0];
  const int*   ei  = (const int*)d_in[1];
  const float* W1  = (const float*)d_in[2];
  const float* as1 = (const float*)d_in[3];
  const float* ad1 = (const float*)d_in[4];
  const float* b1  = (const float*)d_in[5];
  const float* W2  = (const float*)d_in[6];
  const float* as2 = (const float*)d_in[7];
  const float* ad2 = (const float*)d_in[8];
  const float* b2  = (const float*)d_in[9];
  const float* W3  = (const float*)d_in[10];
  const float* as3 = (const float*)d_in[11];
  const float* ad3 = (const float*)d_in[12];
  const float* b3  = (const float*)d_in[13];
  float* out = (float*)d_out;

  char* p = (char*)d_ws;
  auto alloc = [&](size_t bytes) -> char* {
    char* r = p; p += (bytes + 255) & ~(size_t)255; return r;
  };
  int*   cnt    = (int*)alloc((size_t)N_NODES * 4);
  int*   rowptr = (int*)alloc((size_t)(N_NODES + 1) * 4);
  int*   cursor = (int*)alloc((size_t)N_NODES * 4);
  int*   csr    = (int*)alloc((size_t)E_TOT * 4);
  int*   bsum   = (int*)alloc(256 * 4);
  int*   boff   = (int*)alloc(257 * 4);
  float* aS     = (float*)alloc((size_t)N_NODES * 4 * 4);
  float* aD     = (float*)alloc((size_t)N_NODES * 4 * 4);
  float* h3     = (float*)alloc((size_t)N_NODES * 2 * 4);
  float* a3s    = (float*)alloc((size_t)N_NODES * 4);
  float* a3d    = (float*)alloc((size_t)N_NODES * 4);
  float* wtl    = (float*)alloc(1024 * 4);
  unsigned short* xq   = (unsigned short*)alloc((size_t)N_NODES * 128 * 2);
  unsigned short* W1t  = (unsigned short*)alloc((size_t)256 * 128 * 2);
  unsigned short* W2t  = (unsigned short*)alloc((size_t)128 * 256 * 2);
  unsigned short* aggX = (unsigned short*)alloc((size_t)N_NODES * 512 * 2); // 51.2MB
  unsigned short* hBq  = (unsigned short*)alloc((size_t)N_NODES * 256 * 2); // layer1 out
  unsigned short* hq2  = (unsigned short*)alloc((size_t)N_NODES * 128 * 2); // gemm2 out
  float* h2o = (float*)aggX;  // aggr2 out (25.6 MB) aliases dead aggX

  // ---- input conversions + attention projections
  k_f2bf<<<(N_NODES * 128 / 4 + 255) / 256, 256, 0, stream>>>(x, xq, N_NODES * 128 / 4);
  k_wt<128, 256><<<(128 * 256 + 255) / 256, 256, 0, stream>>>(W1, W1t);
  k_wt<256, 128><<<(256 * 128 + 255) / 256, 256, 0, stream>>>(W2, W2t);
  k_wtld<<<2, 256, 0, stream>>>(W1, as1, ad1, wtl);
  k_attx<<<(N_NODES + 3) / 4, 256, 0, stream>>>(x, wtl, aS, aD);

  // ---- CSR (reused by all three layers)
  hipMemsetAsync(cnt, 0, (size_t)N_NODES * 4, stream);
  k_hist<<<(E_TOT + 255) / 256, 256, 0, stream>>>(ei, cnt);
  k_bsum<<<SCAN_B, 256, 0, stream>>>(cnt, bsum);
  k_bscan<<<1, 256, 0, stream>>>(bsum, boff);
  k_rowptr<<<SCAN_B, 256, 0, stream>>>(cnt, boff, rowptr, cursor);
  k_scatter<<<(E_TOT + 255) / 256, 256, 0, stream>>>(ei, cursor, csr);

  const int GB = (N_NODES + 63) / 64;  // 782

  // ---- layer 1 (restructured): aggregate x with alpha, then block-diag GEMM
  k_aggrX<<<(N_NODES + 3) / 4, 256, 0, stream>>>(rowptr, csr, xq, aS, aD, aggX);
  k_gemm_bd<<<dim3(GB, 4), 256, 0, stream>>>(aggX, W1t, b1, hBq, N_NODES);

  // ---- layer 2: 256 -> 2x64, concat, ELU
  k_gemm_mfma<256, 2><<<GB, 256, 0, stream>>>(
      hBq, W2t, as2, ad2, hq2, aS, aD, N_NODES);
  k_aggr<2, true, false><<<(N_NODES + 3) / 4, 256, 0, stream>>>(
      rowptr, csr, hq2, aS, aD, b2, h2o);

  // ---- layer 3: 128 -> 2, mean(1 head), bias, log_softmax
  k_proj3<<<(N_NODES + 255) / 256, 256, 0, stream>>>(h2o, W3, as3, ad3, h3, a3s, a3d);
  k_aggr3<<<(N_NODES + 255) / 256, 256, 0, stream>>>(rowptr, csr, h3, a3s, a3d, b3, out);
}

// Round 8
// 271.081 us; speedup vs baseline: 1.1904x; 1.1904x over previous
//
#include <hip/hip_runtime.h>

#define N_NODES 50000
#define N_EDGES 800000
#define E_TOT   (N_EDGES + N_NODES)   // 850000, self-loops appended at end
#define SCAN_B  ((N_NODES + 255) / 256)  // 196

using bfrag = __attribute__((ext_vector_type(8))) short;
using f32x4 = __attribute__((ext_vector_type(4))) float;

// ---------------------------------------------------------------- bf16 helpers
__device__ __forceinline__ float bflo(unsigned int p) {
  union { unsigned int u; float f; } v; v.u = p << 16; return v.f;
}
__device__ __forceinline__ float bfhi(unsigned int p) {
  union { unsigned int u; float f; } v; v.u = p & 0xFFFF0000u; return v.f;
}
__device__ __forceinline__ unsigned short f2bf(float f) {
  union { float f; unsigned int u; } v; v.f = f;
  unsigned int r = v.u + 0x7FFFu + ((v.u >> 16) & 1u);
  return (unsigned short)(r >> 16);
}
__device__ __forceinline__ void unpack8(uint4 u, float* hv) {
  hv[0] = bflo(u.x); hv[1] = bfhi(u.x);
  hv[2] = bflo(u.y); hv[3] = bfhi(u.y);
  hv[4] = bflo(u.z); hv[5] = bfhi(u.z);
  hv[6] = bflo(u.w); hv[7] = bfhi(u.w);
}

// ---------------------------------------------------------------- conversions
__global__ void k_f2bf(const float* __restrict__ in, unsigned short* __restrict__ out,
                       int n4) {
  int i = blockIdx.x * blockDim.x + threadIdx.x;
  if (i >= n4) return;
  float4 v = *(const float4*)&in[(size_t)i * 4];
  *(ushort4*)&out[(size_t)i * 4] =
      make_ushort4(f2bf(v.x), f2bf(v.y), f2bf(v.z), f2bf(v.w));
}

// W[K][N] fp32 -> Wt[N][K] bf16
template <int K, int N>
__global__ void k_wt(const float* __restrict__ W, unsigned short* __restrict__ Wt) {
  int i = blockIdx.x * blockDim.x + threadIdx.x;
  if (i >= K * N) return;
  int k = i / N, n = i - k * N;
  Wt[n * K + k] = f2bf(W[i]);
}

// ---------------------------------------------------------------- CSR build
__global__ void k_hist(const int* __restrict__ ei, int* __restrict__ cnt) {
  int e = blockIdx.x * blockDim.x + threadIdx.x;
  if (e >= E_TOT) return;
  int d = (e < N_EDGES) ? ei[N_EDGES + e] : (e - N_EDGES);
  atomicAdd(&cnt[d], 1);
}

__global__ void k_bsum(const int* __restrict__ cnt, int* __restrict__ bsum) {
  int t = threadIdx.x;
  int i = blockIdx.x * 256 + t;
  int v = (i < N_NODES) ? cnt[i] : 0;
  #pragma unroll
  for (int off = 32; off; off >>= 1) v += __shfl_down(v, off);
  __shared__ int ws[4];
  if ((t & 63) == 0) ws[t >> 6] = v;
  __syncthreads();
  if (t == 0) bsum[blockIdx.x] = ws[0] + ws[1] + ws[2] + ws[3];
}

__global__ void k_bscan(const int* __restrict__ bsum, int* __restrict__ boff) {
  __shared__ int s[256];
  int t = threadIdx.x;
  int v = (t < SCAN_B) ? bsum[t] : 0;
  s[t] = v;
  __syncthreads();
  for (int off = 1; off < 256; off <<= 1) {
    int x = (t >= off) ? s[t - off] : 0;
    __syncthreads();
    s[t] += x;
    __syncthreads();
  }
  boff[t] = s[t] - v;  // exclusive
}

__global__ void k_rowptr(const int* __restrict__ cnt, const int* __restrict__ boff,
                         int* __restrict__ rowptr, int* __restrict__ cursor) {
  __shared__ int s[256];
  int t = threadIdx.x;
  int i = blockIdx.x * 256 + t;
  int v = (i < N_NODES) ? cnt[i] : 0;
  s[t] = v;
  __syncthreads();
  for (int off = 1; off < 256; off <<= 1) {
    int x = (t >= off) ? s[t - off] : 0;
    __syncthreads();
    s[t] += x;
    __syncthreads();
  }
  int excl = boff[blockIdx.x] + s[t] - v;
  if (i < N_NODES) { rowptr[i] = excl; cursor[i] = excl; }
  if (i == N_NODES - 1) rowptr[N_NODES] = excl + v;
}

__global__ void k_scatter(const int* __restrict__ ei, int* __restrict__ cursor,
                          int* __restrict__ csr) {
  int e = blockIdx.x * blockDim.x + threadIdx.x;
  if (e >= E_TOT) return;
  int s, d;
  if (e < N_EDGES) { s = ei[e]; d = ei[N_EDGES + e]; }
  else             { s = d = e - N_EDGES; }
  int pos = atomicAdd(&cursor[d], 1);
  csr[pos] = s;
}

// ------------------------------------------- MFMA bf16 GEMM + fused epilogue
// Full-width: one block computes ALL H heads (NN = H*64 cols) for 64 rows.
template <int KD, int H>
__global__ __launch_bounds__(256) void k_gemm_mfma(
    const unsigned short* __restrict__ Aq, const unsigned short* __restrict__ Wt,
    const float* __restrict__ atts, const float* __restrict__ attd,
    unsigned short* __restrict__ hq, float* __restrict__ aS,
    float* __restrict__ aD, int M) {
  constexpr int NN = H * 64;
  constexpr int KH = KD / 2;              // K per half
  constexpr int GR = KH / 8;              // 16B granules per col per half
  __shared__ unsigned short Bts[NN * KH]; // 32 KB
  int t = threadIdx.x;
  int lane = t & 63;
  int w = t >> 6;
  int arow = blockIdx.x * 64 + w * 16 + (lane & 15);
  int arow_c = arow < M ? arow : M - 1;
  const unsigned short* Arow = Aq + (size_t)arow_c * KD;

  f32x4 acc[NN / 16] = {};
  #pragma unroll
  for (int half = 0; half < 2; ++half) {
    if (half) __syncthreads();
    #pragma unroll
    for (int c = 0; c < NN * KH / 2048; ++c) {
      int chunk = t + c * 256;
      int col = chunk / GR;
      int kc  = chunk % GR;
      uint4 v = *(const uint4*)&Wt[(size_t)col * KD + half * KH + kc * 8];
      int swz = kc ^ (col & 7);
      *(uint4*)&Bts[col * KH + swz * 8] = v;
    }
    __syncthreads();
    for (int k0 = 0; k0 < KH; k0 += 32) {
      int gl = (k0 >> 3) + (lane >> 4);
      bfrag a = *(const bfrag*)&Arow[half * KH + gl * 8];
      #pragma unroll
      for (int cf = 0; cf < NN / 16; ++cf) {
        int col = cf * 16 + (lane & 15);
        int gs = gl ^ (col & 7);
        bfrag b = *(const bfrag*)&Bts[col * KH + gs * 8];
        acc[cf] = __builtin_amdgcn_mfma_f32_16x16x32_bf16(a, b, acc[cf], 0, 0, 0);
      }
    }
  }

  float ws_[NN / 16], wd_[NN / 16];
  #pragma unroll
  for (int cf = 0; cf < NN / 16; ++cf) {
    ws_[cf] = atts[cf * 16 + (lane & 15)];
    wd_[cf] = attd[cf * 16 + (lane & 15)];
  }
  int orow0 = blockIdx.x * 64 + w * 16 + (lane >> 4) * 4;
  #pragma unroll
  for (int hh = 0; hh < H; ++hh) {
    float ps[4] = {}, pd[4] = {};
    #pragma unroll
    for (int c4 = 0; c4 < 4; ++c4) {
      int cf = hh * 4 + c4;
      #pragma unroll
      for (int i = 0; i < 4; ++i) {
        ps[i] += acc[cf][i] * ws_[cf];
        pd[i] += acc[cf][i] * wd_[cf];
      }
    }
    #pragma unroll
    for (int off = 1; off < 16; off <<= 1)
      #pragma unroll
      for (int i = 0; i < 4; ++i) {
        ps[i] += __shfl_xor(ps[i], off);
        pd[i] += __shfl_xor(pd[i], off);
      }
    if ((lane & 15) == 0)
      #pragma unroll
      for (int i = 0; i < 4; ++i) {
        int r = orow0 + i;
        if (r < M) {
          aS[(size_t)r * H + hh] = ps[i];
          aD[(size_t)r * H + hh] = pd[i];
        }
      }
  }
  #pragma unroll
  for (int i = 0; i < 4; ++i) {
    int r = orow0 + i;
    if (r < M)
      #pragma unroll
      for (int cf = 0; cf < NN / 16; ++cf)
        hq[(size_t)r * NN + cf * 16 + (lane & 15)] = f2bf(acc[cf][i]);
  }
}

// -------------- edge-softmax + aggregate, NO-MAX softmax (logits are small:
// exp(e)/sum exp(e) directly; e in ~[-4,10] << fp32 range). Phase 0 stages
// j + final weight w=exp(leaky(aS+aD)) and accumulates the denominator
// per-lane. Phase 1 is a predication-free 2D gather (chunk padded to EPW).
// One butterfly-sum per node at the end.
template <int H, bool ELU, bool OBF>
__global__ __launch_bounds__(256) void k_aggr(
    const int* __restrict__ rowptr, const int* __restrict__ csr,
    const unsigned short* __restrict__ hq,
    const float* __restrict__ aS, const float* __restrict__ aD,
    const float* __restrict__ bias, void* __restrict__ outv) {
  constexpr int CAP = 64;
  constexpr int C = H * 64;
  constexpr int EPW = 512 / C;      // edges per wave instr: H=4 -> 2, H=2 -> 4
  constexpr int LPE = 64 / EPW;     // lanes per edge
  __shared__ int   jls[4][CAP];
  __shared__ float wls[4][CAP * H];
  int n    = (int)((blockIdx.x * (size_t)blockDim.x + threadIdx.x) >> 6);
  int lane = threadIdx.x & 63;
  int wsl  = threadIdx.x >> 6;
  if (n >= N_NODES) return;
  int* jl  = jls[wsl];
  float* wl = wls[wsl];
  int cg  = lane & (LPE - 1);       // channel group: channels cg*8 .. cg*8+7
  int sub = lane / LPE;             // which edge of the EPW-pack
  int hlc = cg >> 3;                // head owning this lane's channels

  float ad[H];
  #pragma unroll
  for (int h = 0; h < H; ++h) ad[h] = aD[(size_t)n * H + h];

  int lo = rowptr[n], deg = rowptr[n + 1] - lo;
  float sl[H] = {};                 // per-lane partial denominators
  float acc8[8] = {};

  for (int c0 = 0; c0 < deg; c0 += CAP) {
    int cl = deg - c0; if (cl > CAP) cl = CAP;
    int clp = (cl + EPW - 1) & ~(EPW - 1);   // pad to EPW multiple
    // ---- phase 0: stage j + w = exp(leaky(aS+aD)); accumulate denom
    for (int kk = lane; kk < clp; kk += 64) {
      bool v = kk < cl;
      int j = v ? csr[lo + c0 + kk] : n;     // pad: self (valid row), w=0
      jl[kk] = j;
      float e[H];
      if constexpr (H == 4) {
        float4 a4 = *(const float4*)&aS[(size_t)j * 4];
        e[0] = a4.x; e[1] = a4.y; e[2] = a4.z; e[3] = a4.w;
      } else {
        float2 a2 = *(const float2*)&aS[(size_t)j * 2];
        e[0] = a2.x; e[1] = a2.y;
      }
      #pragma unroll
      for (int h = 0; h < H; ++h) {
        float ev = e[h] + ad[h];
        ev = ev > 0.f ? ev : 0.2f * ev;
        float w = v ? __expf(ev) : 0.f;
        sl[h] += w;
        e[h] = w;
      }
      if constexpr (H == 4)
        *(float4*)&wl[kk * 4] = make_float4(e[0], e[1], e[2], e[3]);
      else
        *(float2*)&wl[kk * 2] = make_float2(e[0], e[1]);
    }
    __builtin_amdgcn_wave_barrier();
    // ---- phase 1: predication-free 2D gather-accumulate
    #pragma unroll 4
    for (int k = 0; k < clp; k += EPW) {
      int idx = k + sub;
      int j = jl[idx];
      float wgt = wl[idx * H + hlc];
      uint4 u = *(const uint4*)&hq[(size_t)j * C + cg * 8];
      float hv[8];
      unpack8(u, hv);
      #pragma unroll
      for (int i = 0; i < 8; ++i) acc8[i] += wgt * hv[i];
    }
    __builtin_amdgcn_wave_barrier();
  }

  // single denominator reduction per node
  #pragma unroll
  for (int off = 1; off < 64; off <<= 1)
    #pragma unroll
    for (int h = 0; h < H; ++h) sl[h] += __shfl_xor(sl[h], off);

  // fold the EPW edge-subgroups: lanes with same cg sit at stride LPE
  #pragma unroll
  for (int i = 0; i < 8; ++i) {
    if constexpr (EPW == 4) acc8[i] += __shfl_xor(acc8[i], 16);
    acc8[i] += __shfl_xor(acc8[i], 32);
  }

  if (sub == 0) {
    float inv = 1.f / sl[hlc];
    float o[8];
    #pragma unroll
    for (int i = 0; i < 8; ++i) {
      float v = acc8[i] * inv + bias[cg * 8 + i];
      if (ELU) v = v > 0.f ? v : __expf(v) - 1.f;
      o[i] = v;
    }
    size_t idx = (size_t)n * C + cg * 8;
    if constexpr (OBF) {
      unsigned short* outp = (unsigned short*)outv;
      uint4 r;
      r.x = (unsigned int)f2bf(o[0]) | ((unsigned int)f2bf(o[1]) << 16);
      r.y = (unsigned int)f2bf(o[2]) | ((unsigned int)f2bf(o[3]) << 16);
      r.z = (unsigned int)f2bf(o[4]) | ((unsigned int)f2bf(o[5]) << 16);
      r.w = (unsigned int)f2bf(o[6]) | ((unsigned int)f2bf(o[7]) << 16);
      *(uint4*)&outp[idx] = r;
    } else {
      float* outp = (float*)outv;
      *(float4*)&outp[idx]     = make_float4(o[0], o[1], o[2], o[3]);
      *(float4*)&outp[idx + 4] = make_float4(o[4], o[5], o[6], o[7]);
    }
  }
}

// --------------------------------------------------------- layer-3 (C=2, H=1)
__global__ void k_proj3(const float* __restrict__ hin, const float* __restrict__ W3,
                        const float* __restrict__ s3, const float* __restrict__ d3,
                        float* __restrict__ h3, float* __restrict__ a3s,
                        float* __restrict__ a3d) {
  int n = blockIdx.x * blockDim.x + threadIdx.x;
  if (n >= N_NODES) return;
  float a0 = 0.f, a1 = 0.f;
  const float4* hp = (const float4*)(hin + (size_t)n * 128);
  #pragma unroll
  for (int q = 0; q < 32; ++q) {
    float4 v = hp[q];
    const float* w = W3 + q * 8;
    a0 += v.x * w[0] + v.y * w[2] + v.z * w[4] + v.w * w[6];
    a1 += v.x * w[1] + v.y * w[3] + v.z * w[5] + v.w * w[7];
  }
  h3[(size_t)n * 2]     = a0;
  h3[(size_t)n * 2 + 1] = a1;
  a3s[n] = a0 * s3[0] + a1 * s3[1];
  a3d[n] = a0 * d3[0] + a1 * d3[1];
}

__global__ void k_aggr3(const int* __restrict__ rowptr, const int* __restrict__ csr,
                        const float* __restrict__ h3, const float* __restrict__ a3s,
                        const float* __restrict__ a3d, const float* __restrict__ b3,
                        float* __restrict__ out) {
  int n = blockIdx.x * blockDim.x + threadIdx.x;
  if (n >= N_NODES) return;
  float adv = a3d[n];
  float s = 0.f, acc0 = 0.f, acc1 = 0.f;
  int lo = rowptr[n], hi = rowptr[n + 1];
  for (int k = lo; k < hi; ++k) {
    int j = csr[k];
    float e = a3s[j] + adv;
    e = e > 0.f ? e : 0.2f * e;
    float w = __expf(e);           // no-max softmax (logits small)
    float h0 = h3[(size_t)j * 2], h1 = h3[(size_t)j * 2 + 1];
    s += w; acc0 += w * h0; acc1 += w * h1;
  }
  float o0 = acc0 / s + b3[0];
  float o1 = acc1 / s + b3[1];
  float mx = fmaxf(o0, o1);
  float l  = logf(__expf(o0 - mx) + __expf(o1 - mx));
  out[(size_t)n * 2]     = o0 - mx - l;
  out[(size_t)n * 2 + 1] = o1 - mx - l;
}

// ---------------------------------------------------------------- launcher
extern "C" void kernel_launch(void* const* d_in, const int* in_sizes, int n_in,
                              void* d_out, int out_size, void* d_ws, size_t ws_size,
                              hipStream_t stream) {
  const float* x   = (const float*)d_in[0];
  const int*   ei  = (const int*)d_in[1];
  const float* W1  = (const float*)d_in[2];
  const float* as1 = (const float*)d_in[3];
  const float* ad1 = (const float*)d_in[4];
  const float* b1  = (const float*)d_in[5];
  const float* W2  = (const float*)d_in[6];
  const float* as2 = (const float*)d_in[7];
  const float* ad2 = (const float*)d_in[8];
  const float* b2  = (const float*)d_in[9];
  const float* W3  = (const float*)d_in[10];
  const float* as3 = (const float*)d_in[11];
  const float* ad3 = (const float*)d_in[12];
  const float* b3  = (const float*)d_in[13];
  float* out = (float*)d_out;

  char* p = (char*)d_ws;
  auto alloc = [&](size_t bytes) -> char* {
    char* r = p; p += (bytes + 255) & ~(size_t)255; return r;
  };
  int*   cnt    = (int*)alloc((size_t)N_NODES * 4);
  int*   rowptr = (int*)alloc((size_t)(N_NODES + 1) * 4);
  int*   cursor = (int*)alloc((size_t)N_NODES * 4);
  int*   csr    = (int*)alloc((size_t)E_TOT * 4);
  int*   bsum   = (int*)alloc(256 * 4);
  int*   boff   = (int*)alloc(257 * 4);
  float* aS     = (float*)alloc((size_t)N_NODES * 4 * 4);
  float* aD     = (float*)alloc((size_t)N_NODES * 4 * 4);
  float* h3     = (float*)alloc((size_t)N_NODES * 2 * 4);
  float* a3s    = (float*)alloc((size_t)N_NODES * 4);
  float* a3d    = (float*)alloc((size_t)N_NODES * 4);
  unsigned short* xq  = (unsigned short*)alloc((size_t)N_NODES * 128 * 2);
  unsigned short* W1t = (unsigned short*)alloc((size_t)256 * 128 * 2);
  unsigned short* W2t = (unsigned short*)alloc((size_t)128 * 256 * 2);
  unsigned short* hq1 = (unsigned short*)alloc((size_t)N_NODES * 256 * 2);  // gemm1 out
  unsigned short* hBq = (unsigned short*)alloc((size_t)N_NODES * 256 * 2);  // aggr1 out
  unsigned short* hq2 = (unsigned short*)alloc((size_t)N_NODES * 128 * 2);  // gemm2 out
  float* h2o = (float*)hq1;  // aggr2 out (25.6 MB) aliases dead hq1

  // ---- input conversions (bf16)
  k_f2bf<<<(N_NODES * 128 / 4 + 255) / 256, 256, 0, stream>>>(x, xq, N_NODES * 128 / 4);
  k_wt<128, 256><<<(128 * 256 + 255) / 256, 256, 0, stream>>>(W1, W1t);
  k_wt<256, 128><<<(256 * 128 + 255) / 256, 256, 0, stream>>>(W2, W2t);

  // ---- CSR (reused by all three layers)
  hipMemsetAsync(cnt, 0, (size_t)N_NODES * 4, stream);
  k_hist<<<(E_TOT + 255) / 256, 256, 0, stream>>>(ei, cnt);
  k_bsum<<<SCAN_B, 256, 0, stream>>>(cnt, bsum);
  k_bscan<<<1, 256, 0, stream>>>(bsum, boff);
  k_rowptr<<<SCAN_B, 256, 0, stream>>>(cnt, boff, rowptr, cursor);
  k_scatter<<<(E_TOT + 255) / 256, 256, 0, stream>>>(ei, cursor, csr);

  const int GB = (N_NODES + 63) / 64;  // 782

  // ---- layer 1: 128 -> 4x64, concat, ELU
  k_gemm_mfma<128, 4><<<GB, 256, 0, stream>>>(
      xq, W1t, as1, ad1, hq1, aS, aD, N_NODES);
  k_aggr<4, true, true><<<(N_NODES + 3) / 4, 256, 0, stream>>>(
      rowptr, csr, hq1, aS, aD, b1, hBq);

  // ---- layer 2: 256 -> 2x64, concat, ELU
  k_gemm_mfma<256, 2><<<GB, 256, 0, stream>>>(
      hBq, W2t, as2, ad2, hq2, aS, aD, N_NODES);
  k_aggr<2, true, false><<<(N_NODES + 3) / 4, 256, 0, stream>>>(
      rowptr, csr, hq2, aS, aD, b2, h2o);

  // ---- layer 3: 128 -> 2, mean(1 head), bias, log_softmax
  k_proj3<<<(N_NODES + 255) / 256, 256, 0, stream>>>(h2o, W3, as3, ad3, h3, a3s, a3d);
  k_aggr3<<<(N_NODES + 255) / 256, 256, 0, stream>>>(rowptr, csr, h3, a3s, a3d, b3, out);
}

// Round 9
// 254.714 us; speedup vs baseline: 1.2669x; 1.0643x over previous
//
#include <hip/hip_runtime.h>

#define N_NODES 50000
#define N_EDGES 800000
#define E_TOT   (N_EDGES + N_NODES)   // 850000, self-loops appended at end
#define SCAN_B  ((N_NODES + 255) / 256)  // 196

using bfrag = __attribute__((ext_vector_type(8))) short;
using f32x4 = __attribute__((ext_vector_type(4))) float;

// ---------------------------------------------------------------- bf16 helpers
__device__ __forceinline__ float bflo(unsigned int p) {
  union { unsigned int u; float f; } v; v.u = p << 16; return v.f;
}
__device__ __forceinline__ float bfhi(unsigned int p) {
  union { unsigned int u; float f; } v; v.u = p & 0xFFFF0000u; return v.f;
}
__device__ __forceinline__ unsigned short f2bf(float f) {
  union { float f; unsigned int u; } v; v.f = f;
  unsigned int r = v.u + 0x7FFFu + ((v.u >> 16) & 1u);
  return (unsigned short)(r >> 16);
}
__device__ __forceinline__ void unpack8(uint4 u, float* hv) {
  hv[0] = bflo(u.x); hv[1] = bfhi(u.x);
  hv[2] = bflo(u.y); hv[3] = bfhi(u.y);
  hv[4] = bflo(u.z); hv[5] = bfhi(u.z);
  hv[6] = bflo(u.w); hv[7] = bfhi(u.w);
}

// ------------------------------------------- fused conversions (one kernel)
// [0, 1.6M): x -> xq as float4 chunks; then W1 (128x256) -> W1t[n][k];
// then W2 (256x128) -> W2t[n][k].
#define CONV_X4 (N_NODES * 128 / 4)              // 1,600,000
#define CONV_W1 (CONV_X4 + 128 * 256)            // + 32768
#define CONV_W2 (CONV_W1 + 256 * 128)            // + 32768
__global__ void k_conv(const float* __restrict__ x, const float* __restrict__ W1,
                       const float* __restrict__ W2, unsigned short* __restrict__ xq,
                       unsigned short* __restrict__ W1t, unsigned short* __restrict__ W2t) {
  int i = blockIdx.x * blockDim.x + threadIdx.x;
  if (i < CONV_X4) {
    float4 v = *(const float4*)&x[(size_t)i * 4];
    *(ushort4*)&xq[(size_t)i * 4] =
        make_ushort4(f2bf(v.x), f2bf(v.y), f2bf(v.z), f2bf(v.w));
  } else if (i < CONV_W1) {
    int j = i - CONV_X4;
    int k = j >> 8, n = j & 255;
    W1t[n * 128 + k] = f2bf(W1[j]);
  } else if (i < CONV_W2) {
    int j = i - CONV_W1;
    int k = j >> 7, n = j & 127;
    W2t[n * 256 + k] = f2bf(W2[j]);
  }
}

// ---------------------------------------------------------------- CSR build
__global__ void k_hist(const int* __restrict__ ei, int* __restrict__ cnt) {
  int e = blockIdx.x * blockDim.x + threadIdx.x;
  if (e >= E_TOT) return;
  int d = (e < N_EDGES) ? ei[N_EDGES + e] : (e - N_EDGES);
  atomicAdd(&cnt[d], 1);
}

__global__ void k_bsum(const int* __restrict__ cnt, int* __restrict__ bsum) {
  int t = threadIdx.x;
  int i = blockIdx.x * 256 + t;
  int v = (i < N_NODES) ? cnt[i] : 0;
  #pragma unroll
  for (int off = 32; off; off >>= 1) v += __shfl_down(v, off);
  __shared__ int ws[4];
  if ((t & 63) == 0) ws[t >> 6] = v;
  __syncthreads();
  if (t == 0) bsum[blockIdx.x] = ws[0] + ws[1] + ws[2] + ws[3];
}

__global__ void k_bscan(const int* __restrict__ bsum, int* __restrict__ boff) {
  __shared__ int s[256];
  int t = threadIdx.x;
  int v = (t < SCAN_B) ? bsum[t] : 0;
  s[t] = v;
  __syncthreads();
  for (int off = 1; off < 256; off <<= 1) {
    int x = (t >= off) ? s[t - off] : 0;
    __syncthreads();
    s[t] += x;
    __syncthreads();
  }
  boff[t] = s[t] - v;  // exclusive
}

__global__ void k_rowptr(const int* __restrict__ cnt, const int* __restrict__ boff,
                         int* __restrict__ rowptr, int* __restrict__ cursor) {
  __shared__ int s[256];
  int t = threadIdx.x;
  int i = blockIdx.x * 256 + t;
  int v = (i < N_NODES) ? cnt[i] : 0;
  s[t] = v;
  __syncthreads();
  for (int off = 1; off < 256; off <<= 1) {
    int x = (t >= off) ? s[t - off] : 0;
    __syncthreads();
    s[t] += x;
    __syncthreads();
  }
  int excl = boff[blockIdx.x] + s[t] - v;
  if (i < N_NODES) { rowptr[i] = excl; cursor[i] = excl; }
  if (i == N_NODES - 1) rowptr[N_NODES] = excl + v;
}

__global__ void k_scatter(const int* __restrict__ ei, int* __restrict__ cursor,
                          int* __restrict__ csr) {
  int e = blockIdx.x * blockDim.x + threadIdx.x;
  if (e >= E_TOT) return;
  int s, d;
  if (e < N_EDGES) { s = ei[e]; d = ei[N_EDGES + e]; }
  else             { s = d = e - N_EDGES; }
  int pos = atomicAdd(&cursor[d], 1);
  csr[pos] = s;
}

// ------------------------------------------- MFMA bf16 GEMM + fused epilogue
// ROWS rows per block (ROWS/16 waves x 16 rows), all H heads full-width.
template <int KD, int H, int ROWS>
__global__ __launch_bounds__(ROWS * 4) void k_gemm_mfma(
    const unsigned short* __restrict__ Aq, const unsigned short* __restrict__ Wt,
    const float* __restrict__ atts, const float* __restrict__ attd,
    unsigned short* __restrict__ hq, float* __restrict__ aS,
    float* __restrict__ aD, int M) {
  constexpr int NN = H * 64;
  constexpr int KH = KD / 2;              // K per half
  constexpr int GR = KH / 8;              // 16B granules per col per half
  constexpr int T  = ROWS * 4;            // threads
  __shared__ unsigned short Bts[NN * KH]; // 32 KB
  int t = threadIdx.x;
  int lane = t & 63;
  int w = t >> 6;
  int arow = blockIdx.x * ROWS + w * 16 + (lane & 15);
  int arow_c = arow < M ? arow : M - 1;
  const unsigned short* Arow = Aq + (size_t)arow_c * KD;

  f32x4 acc[NN / 16] = {};
  #pragma unroll
  for (int half = 0; half < 2; ++half) {
    if (half) __syncthreads();
    #pragma unroll
    for (int c = 0; c < NN * KH / 8 / T; ++c) {
      int chunk = t + c * T;
      int col = chunk / GR;
      int kc  = chunk % GR;
      uint4 v = *(const uint4*)&Wt[(size_t)col * KD + half * KH + kc * 8];
      int swz = kc ^ (col & 7);
      *(uint4*)&Bts[col * KH + swz * 8] = v;
    }
    __syncthreads();
    for (int k0 = 0; k0 < KH; k0 += 32) {
      int gl = (k0 >> 3) + (lane >> 4);
      bfrag a = *(const bfrag*)&Arow[half * KH + gl * 8];
      #pragma unroll
      for (int cf = 0; cf < NN / 16; ++cf) {
        int col = cf * 16 + (lane & 15);
        int gs = gl ^ (col & 7);
        bfrag b = *(const bfrag*)&Bts[col * KH + gs * 8];
        acc[cf] = __builtin_amdgcn_mfma_f32_16x16x32_bf16(a, b, acc[cf], 0, 0, 0);
      }
    }
  }

  float ws_[NN / 16], wd_[NN / 16];
  #pragma unroll
  for (int cf = 0; cf < NN / 16; ++cf) {
    ws_[cf] = atts[cf * 16 + (lane & 15)];
    wd_[cf] = attd[cf * 16 + (lane & 15)];
  }
  int orow0 = blockIdx.x * ROWS + w * 16 + (lane >> 4) * 4;
  #pragma unroll
  for (int hh = 0; hh < H; ++hh) {
    float ps[4] = {}, pd[4] = {};
    #pragma unroll
    for (int c4 = 0; c4 < 4; ++c4) {
      int cf = hh * 4 + c4;
      #pragma unroll
      for (int i = 0; i < 4; ++i) {
        ps[i] += acc[cf][i] * ws_[cf];
        pd[i] += acc[cf][i] * wd_[cf];
      }
    }
    #pragma unroll
    for (int off = 1; off < 16; off <<= 1)
      #pragma unroll
      for (int i = 0; i < 4; ++i) {
        ps[i] += __shfl_xor(ps[i], off);
        pd[i] += __shfl_xor(pd[i], off);
      }
    if ((lane & 15) == 0)
      #pragma unroll
      for (int i = 0; i < 4; ++i) {
        int r = orow0 + i;
        if (r < M) {
          aS[(size_t)r * H + hh] = ps[i];
          aD[(size_t)r * H + hh] = pd[i];
        }
      }
  }
  #pragma unroll
  for (int i = 0; i < 4; ++i) {
    int r = orow0 + i;
    if (r < M)
      #pragma unroll
      for (int cf = 0; cf < NN / 16; ++cf)
        hq[(size_t)r * NN + cf * 16 + (lane & 15)] = f2bf(acc[cf][i]);
  }
}

// -------------- edge-softmax + aggregate, NO-MAX softmax. Phase 0 stages
// j + w=exp(leaky(aS+aD)), per-lane denom. Phase 1: predication-free 2D
// gather. PROJ3: fuse the layer-3 projection into the epilogue (write
// h3/a3s/a3d instead of the 25MB h2 intermediate).
template <int H, bool ELU, bool OBF, bool PROJ3>
__global__ __launch_bounds__(256) void k_aggr(
    const int* __restrict__ rowptr, const int* __restrict__ csr,
    const unsigned short* __restrict__ hq,
    const float* __restrict__ aS, const float* __restrict__ aD,
    const float* __restrict__ bias, void* __restrict__ outv,
    const float* __restrict__ W3, const float* __restrict__ s3,
    const float* __restrict__ d3, float* __restrict__ h3o,
    float* __restrict__ a3so, float* __restrict__ a3do) {
  constexpr int CAP = 64;
  constexpr int C = H * 64;
  constexpr int EPW = 512 / C;      // edges per wave instr: H=4 -> 2, H=2 -> 4
  constexpr int LPE = 64 / EPW;     // lanes per edge
  __shared__ int   jls[4][CAP];
  __shared__ float wls[4][CAP * H];
  int n    = (int)((blockIdx.x * (size_t)blockDim.x + threadIdx.x) >> 6);
  int lane = threadIdx.x & 63;
  int wsl  = threadIdx.x >> 6;
  if (n >= N_NODES) return;
  int* jl  = jls[wsl];
  float* wl = wls[wsl];
  int cg  = lane & (LPE - 1);       // channel group: channels cg*8 .. cg*8+7
  int sub = lane / LPE;             // which edge of the EPW-pack
  int hlc = cg >> 3;                // head owning this lane's channels

  float ad[H];
  #pragma unroll
  for (int h = 0; h < H; ++h) ad[h] = aD[(size_t)n * H + h];

  int lo = rowptr[n], deg = rowptr[n + 1] - lo;
  float sl[H] = {};                 // per-lane partial denominators
  float acc8[8] = {};

  for (int c0 = 0; c0 < deg; c0 += CAP) {
    int cl = deg - c0; if (cl > CAP) cl = CAP;
    int clp = (cl + EPW - 1) & ~(EPW - 1);   // pad to EPW multiple
    // ---- phase 0: stage j + w = exp(leaky(aS+aD)); accumulate denom
    for (int kk = lane; kk < clp; kk += 64) {
      bool v = kk < cl;
      int j = v ? csr[lo + c0 + kk] : n;     // pad: self (valid row), w=0
      jl[kk] = j;
      float e[H];
      if constexpr (H == 4) {
        float4 a4 = *(const float4*)&aS[(size_t)j * 4];
        e[0] = a4.x; e[1] = a4.y; e[2] = a4.z; e[3] = a4.w;
      } else {
        float2 a2 = *(const float2*)&aS[(size_t)j * 2];
        e[0] = a2.x; e[1] = a2.y;
      }
      #pragma unroll
      for (int h = 0; h < H; ++h) {
        float ev = e[h] + ad[h];
        ev = ev > 0.f ? ev : 0.2f * ev;
        float w = v ? __expf(ev) : 0.f;
        sl[h] += w;
        e[h] = w;
      }
      if constexpr (H == 4)
        *(float4*)&wl[kk * 4] = make_float4(e[0], e[1], e[2], e[3]);
      else
        *(float2*)&wl[kk * 2] = make_float2(e[0], e[1]);
    }
    __builtin_amdgcn_wave_barrier();
    // ---- phase 1: predication-free 2D gather-accumulate
    #pragma unroll 4
    for (int k = 0; k < clp; k += EPW) {
      int idx = k + sub;
      int j = jl[idx];
      float wgt = wl[idx * H + hlc];
      uint4 u = *(const uint4*)&hq[(size_t)j * C + cg * 8];
      float hv[8];
      unpack8(u, hv);
      #pragma unroll
      for (int i = 0; i < 8; ++i) acc8[i] += wgt * hv[i];
    }
    __builtin_amdgcn_wave_barrier();
  }

  // single denominator reduction per node (all lanes end with totals)
  #pragma unroll
  for (int off = 1; off < 64; off <<= 1)
    #pragma unroll
    for (int h = 0; h < H; ++h) sl[h] += __shfl_xor(sl[h], off);

  // fold the EPW edge-subgroups: all lanes end with folded totals
  #pragma unroll
  for (int i = 0; i < 8; ++i) {
    if constexpr (EPW == 4) acc8[i] += __shfl_xor(acc8[i], 16);
    acc8[i] += __shfl_xor(acc8[i], 32);
  }

  float inv = 1.f / sl[hlc];
  float o[8];
  #pragma unroll
  for (int i = 0; i < 8; ++i) {
    float v = acc8[i] * inv + bias[cg * 8 + i];
    if (ELU) v = v > 0.f ? v : __expf(v) - 1.f;
    o[i] = v;
  }

  if constexpr (PROJ3) {
    // fused layer-3 projection: h3 = o . W3 (128x2), a3s/a3d from h3
    float a0 = 0.f, a1 = 0.f;
    #pragma unroll
    for (int i = 0; i < 8; ++i) {
      int c = cg * 8 + i;
      a0 += o[i] * W3[c * 2 + 0];
      a1 += o[i] * W3[c * 2 + 1];
    }
    #pragma unroll
    for (int off = 1; off < 16; off <<= 1) {
      a0 += __shfl_xor(a0, off);
      a1 += __shfl_xor(a1, off);
    }
    if (lane == 0) {
      h3o[(size_t)n * 2]     = a0;
      h3o[(size_t)n * 2 + 1] = a1;
      a3so[n] = a0 * s3[0] + a1 * s3[1];
      a3do[n] = a0 * d3[0] + a1 * d3[1];
    }
  } else if (sub == 0) {
    size_t idx = (size_t)n * C + cg * 8;
    if constexpr (OBF) {
      unsigned short* outp = (unsigned short*)outv;
      uint4 r;
      r.x = (unsigned int)f2bf(o[0]) | ((unsigned int)f2bf(o[1]) << 16);
      r.y = (unsigned int)f2bf(o[2]) | ((unsigned int)f2bf(o[3]) << 16);
      r.z = (unsigned int)f2bf(o[4]) | ((unsigned int)f2bf(o[5]) << 16);
      r.w = (unsigned int)f2bf(o[6]) | ((unsigned int)f2bf(o[7]) << 16);
      *(uint4*)&outp[idx] = r;
    } else {
      float* outp = (float*)outv;
      *(float4*)&outp[idx]     = make_float4(o[0], o[1], o[2], o[3]);
      *(float4*)&outp[idx + 4] = make_float4(o[4], o[5], o[6], o[7]);
    }
  }
}

// --------------------------------------------------------- layer-3 aggregate
__global__ void k_aggr3(const int* __restrict__ rowptr, const int* __restrict__ csr,
                        const float* __restrict__ h3, const float* __restrict__ a3s,
                        const float* __restrict__ a3d, const float* __restrict__ b3,
                        float* __restrict__ out) {
  int n = blockIdx.x * blockDim.x + threadIdx.x;
  if (n >= N_NODES) return;
  float adv = a3d[n];
  float s = 0.f, acc0 = 0.f, acc1 = 0.f;
  int lo = rowptr[n], hi = rowptr[n + 1];
  for (int k = lo; k < hi; ++k) {
    int j = csr[k];
    float e = a3s[j] + adv;
    e = e > 0.f ? e : 0.2f * e;
    float w = __expf(e);           // no-max softmax (logits small)
    float2 h = *(const float2*)&h3[(size_t)j * 2];
    s += w; acc0 += w * h.x; acc1 += w * h.y;
  }
  float o0 = acc0 / s + b3[0];
  float o1 = acc1 / s + b3[1];
  float mx = fmaxf(o0, o1);
  float l  = logf(__expf(o0 - mx) + __expf(o1 - mx));
  out[(size_t)n * 2]     = o0 - mx - l;
  out[(size_t)n * 2 + 1] = o1 - mx - l;
}

// ---------------------------------------------------------------- launcher
extern "C" void kernel_launch(void* const* d_in, const int* in_sizes, int n_in,
                              void* d_out, int out_size, void* d_ws, size_t ws_size,
                              hipStream_t stream) {
  const float* x   = (const float*)d_in[0];
  const int*   ei  = (const int*)d_in[1];
  const float* W1  = (const float*)d_in[2];
  const float* as1 = (const float*)d_in[3];
  const float* ad1 = (const float*)d_in[4];
  const float* b1  = (const float*)d_in[5];
  const float* W2  = (const float*)d_in[6];
  const float* as2 = (const float*)d_in[7];
  const float* ad2 = (const float*)d_in[8];
  const float* b2  = (const float*)d_in[9];
  const float* W3  = (const float*)d_in[10];
  const float* as3 = (const float*)d_in[11];
  const float* ad3 = (const float*)d_in[12];
  const float* b3  = (const float*)d_in[13];
  float* out = (float*)d_out;

  char* p = (char*)d_ws;
  auto alloc = [&](size_t bytes) -> char* {
    char* r = p; p += (bytes + 255) & ~(size_t)255; return r;
  };
  int*   cnt    = (int*)alloc((size_t)N_NODES * 4);
  int*   rowptr = (int*)alloc((size_t)(N_NODES + 1) * 4);
  int*   cursor = (int*)alloc((size_t)N_NODES * 4);
  int*   csr    = (int*)alloc((size_t)E_TOT * 4);
  int*   bsum   = (int*)alloc(256 * 4);
  int*   boff   = (int*)alloc(257 * 4);
  float* aS     = (float*)alloc((size_t)N_NODES * 4 * 4);
  float* aD     = (float*)alloc((size_t)N_NODES * 4 * 4);
  float* h3     = (float*)alloc((size_t)N_NODES * 2 * 4);
  float* a3s    = (float*)alloc((size_t)N_NODES * 4);
  float* a3d    = (float*)alloc((size_t)N_NODES * 4);
  unsigned short* xq  = (unsigned short*)alloc((size_t)N_NODES * 128 * 2);
  unsigned short* W1t = (unsigned short*)alloc((size_t)256 * 128 * 2);
  unsigned short* W2t = (unsigned short*)alloc((size_t)128 * 256 * 2);
  unsigned short* hq1 = (unsigned short*)alloc((size_t)N_NODES * 256 * 2);  // gemm1 out
  unsigned short* hBq = (unsigned short*)alloc((size_t)N_NODES * 256 * 2);  // aggr1 out
  unsigned short* hq2 = (unsigned short*)alloc((size_t)N_NODES * 128 * 2);  // gemm2 out

  // ---- fused input conversions (bf16)
  k_conv<<<(CONV_W2 + 255) / 256, 256, 0, stream>>>(x, W1, W2, xq, W1t, W2t);

  // ---- CSR (reused by all three layers)
  hipMemsetAsync(cnt, 0, (size_t)N_NODES * 4, stream);
  k_hist<<<(E_TOT + 255) / 256, 256, 0, stream>>>(ei, cnt);
  k_bsum<<<SCAN_B, 256, 0, stream>>>(cnt, bsum);
  k_bscan<<<1, 256, 0, stream>>>(bsum, boff);
  k_rowptr<<<SCAN_B, 256, 0, stream>>>(cnt, boff, rowptr, cursor);
  k_scatter<<<(E_TOT + 255) / 256, 256, 0, stream>>>(ei, cursor, csr);

  const int GB = (N_NODES + 127) / 128;  // 391

  // ---- layer 1: 128 -> 4x64, concat, ELU
  k_gemm_mfma<128, 4, 128><<<GB, 512, 0, stream>>>(
      xq, W1t, as1, ad1, hq1, aS, aD, N_NODES);
  k_aggr<4, true, true, false><<<(N_NODES + 3) / 4, 256, 0, stream>>>(
      rowptr, csr, hq1, aS, aD, b1, hBq,
      nullptr, nullptr, nullptr, nullptr, nullptr, nullptr);

  // ---- layer 2: 256 -> 2x64, concat, ELU; epilogue fuses layer-3 projection
  k_gemm_mfma<256, 2, 128><<<GB, 512, 0, stream>>>(
      hBq, W2t, as2, ad2, hq2, aS, aD, N_NODES);
  k_aggr<2, true, false, true><<<(N_NODES + 3) / 4, 256, 0, stream>>>(
      rowptr, csr, hq2, aS, aD, b2, nullptr,
      W3, as3, ad3, h3, a3s, a3d);

  // ---- layer 3 aggregate + log_softmax
  k_aggr3<<<(N_NODES + 255) / 256, 256, 0, stream>>>(rowptr, csr, h3, a3s, a3d, b3, out);
}